// Round 5
// baseline (347.425 us; speedup 1.0000x reference)
//
#include <hip/hip_runtime.h>
#include <cmath>

// Decoder: 3-layer GRU (B=16, H=2048, E=128) + vocab projection (V=32000) + log_softmax.
// Memory-bound: 516 MB fp32 weights streamed once. Roofline ~78us @ ~6.8 TB/s.
//
// Round 1-4 lesson: wave loads that touch multiple address segments (lane=(kk,rg)
// patterns: 4 segments 8KB apart, or 4x lane-duplicated) cost ~40-64 cyc of
// per-CU vmem-pipe time each vs ~8 cyc for a contiguous 1KB load (the harness
// fill kernel, pure contiguous dwordx4, hits 88% HBM peak). This version makes
// EVERY load contiguous: lane L reads W[row][it*256+L*4] (1KB/instr), x read the
// same way into registers and reused across R=8 rows. No LDS, no barriers.
// Dot spans 64 lanes -> 4-step butterfly + sel16 transpose + 2-step finish.

#define BB 16
#define HH 2048
#define EE 128
#define VV 32000
#define G3H (3 * HH)

__device__ __forceinline__ void fma4(float& a, const float4 w, const float4 x) {
  a = fmaf(w.x, x.x, a); a = fmaf(w.y, x.y, a);
  a = fmaf(w.z, x.z, a); a = fmaf(w.w, x.w, a);
}

// static-index selects (cndmask trees; no runtime-indexed register arrays)
__device__ __forceinline__ float sel4f(float a, float b, float c, float d, int i) {
  float x = (i & 1) ? b : a;
  float y = (i & 1) ? d : c;
  return (i & 2) ? y : x;
}
__device__ __forceinline__ float sel16(const float a[16], int i) {
  float s0 = (i & 1) ? a[1]  : a[0];
  float s1 = (i & 1) ? a[3]  : a[2];
  float s2 = (i & 1) ? a[5]  : a[4];
  float s3 = (i & 1) ? a[7]  : a[6];
  float s4 = (i & 1) ? a[9]  : a[8];
  float s5 = (i & 1) ? a[11] : a[10];
  float s6 = (i & 1) ? a[13] : a[12];
  float s7 = (i & 1) ? a[15] : a[14];
  float t0 = (i & 2) ? s1 : s0;
  float t1 = (i & 2) ? s3 : s2;
  float t2 = (i & 2) ? s5 : s4;
  float t3 = (i & 2) ? s7 : s6;
  float u0 = (i & 4) ? t1 : t0;
  float u1 = (i & 4) ? t3 : t2;
  return (i & 8) ? u1 : u0;
}

// Core: 8 rows x DIM=2048 GEMV vs x(16,2048), all loads contiguous 1KB/instr.
// Lane L covers k = it*256 + L*4. Ends with full dots written to dst[b*ldd+row].
template<bool BIAS>
__device__ __forceinline__
void gemv8(const float* __restrict__ x, const float* __restrict__ W,
           const float* __restrict__ bias, float* __restrict__ dst,
           int ldd, int row0, int lane)
{
  float acc[8][16];
  #pragma unroll
  for (int r = 0; r < 8; ++r)
    #pragma unroll
    for (int b = 0; b < 16; ++b) acc[r][b] = 0.f;

  const int kb = lane * 4;
  #pragma unroll 1
  for (int it = 0; it < 8; ++it) {
    const int k = it * 256 + kb;
    float4 xv[16];
    #pragma unroll
    for (int b = 0; b < 16; ++b)
      xv[b] = *(const float4*)(x + b * HH + k);
    #pragma unroll
    for (int r = 0; r < 8; ++r) {
      const float4 wv = *(const float4*)(W + (size_t)(row0 + r) * HH + k);
      #pragma unroll
      for (int b = 0; b < 16; ++b) fma4(acc[r][b], wv, xv[b]);
    }
  }

  // 4-step butterfly (masks 4,8,16,32): lane L holds partial over k-lanes == L%4 (mod 4)
  #pragma unroll
  for (int r = 0; r < 8; ++r) {
    #pragma unroll
    for (int b = 0; b < 16; ++b) {
      float a = acc[r][b];
      a += __shfl_xor(a, 4, 64);
      a += __shfl_xor(a, 8, 64);
      a += __shfl_xor(a, 16, 64);
      a += __shfl_xor(a, 32, 64);
      acc[r][b] = a;
    }
  }

  // transpose: lane L extracts b = L>>2 column for all 8 rows, then sums its 4-lane group
  const int b = lane >> 2;
  const int rl = lane & 3;
  float v[8];
  #pragma unroll
  for (int r = 0; r < 8; ++r) {
    float t = sel16(acc[r], b);
    t += __shfl_xor(t, 1, 64);
    t += __shfl_xor(t, 2, 64);
    v[r] = t;
  }
  float o0 = sel4f(v[0], v[1], v[2], v[3], rl);
  float o1 = sel4f(v[4], v[5], v[6], v[7], rl);
  if (BIAS) {
    o0 += bias[row0 + rl];
    o1 += bias[row0 + 4 + rl];
  }
  dst[(size_t)b * ldd + row0 + rl] = o0;
  dst[(size_t)b * ldd + row0 + 4 + rl] = o1;
}

// Layer 0: blocks [0,128): gi = relu(emb[tok]) @ Wih0^T (3MB, DIM=128, (kk,rg) path);
//          blocks [128,320): gh = h0 @ Whh0^T (50MB, gemv8).
__global__ __launch_bounds__(256, 2)
void gru_l0(const float* __restrict__ emb, const int* __restrict__ tokens,
            const float* __restrict__ h0,
            const float* __restrict__ Wih0, const float* __restrict__ Whh0,
            float* __restrict__ gi, float* __restrict__ gh)
{
  const int tid  = threadIdx.x;
  const int lane = tid & 63;
  const int wv   = tid >> 6;
  const int bx   = blockIdx.x;

  if (bx < 128) {
    // 512 waves, 12 rows each (rg owns 3). DIM=128: it = 0..1.
    const int kk = lane & 15;
    const int rg = lane >> 4;
    const int u  = bx * 4 + wv;
    const int row0 = u * 12 + rg * 3;
    float acc[3][16];
    #pragma unroll
    for (int r = 0; r < 3; ++r)
      #pragma unroll
      for (int b = 0; b < 16; ++b) acc[r][b] = 0.f;

    #pragma unroll
    for (int it = 0; it < 2; ++it) {
      const int k = it * 64 + kk * 4;
      const float4 w0 = *(const float4*)(Wih0 + (size_t)row0 * EE + k);
      const float4 w1 = *(const float4*)(Wih0 + (size_t)(row0 + 1) * EE + k);
      const float4 w2 = *(const float4*)(Wih0 + (size_t)(row0 + 2) * EE + k);
      #pragma unroll
      for (int b = 0; b < 16; ++b) {
        float4 xv = *(const float4*)(emb + (size_t)tokens[b] * EE + k);
        xv.x = fmaxf(xv.x, 0.f); xv.y = fmaxf(xv.y, 0.f);
        xv.z = fmaxf(xv.z, 0.f); xv.w = fmaxf(xv.w, 0.f);
        fma4(acc[0][b], w0, xv);
        fma4(acc[1][b], w1, xv);
        fma4(acc[2][b], w2, xv);
      }
    }
    #pragma unroll
    for (int r = 0; r < 3; ++r) {
      #pragma unroll
      for (int b = 0; b < 16; ++b) {
        float a = acc[r][b];
        a += __shfl_xor(a, 1, 64);
        a += __shfl_xor(a, 2, 64);
        a += __shfl_xor(a, 4, 64);
        a += __shfl_xor(a, 8, 64);
        acc[r][b] = a;
      }
    }
    #pragma unroll
    for (int r = 0; r < 3; ++r)
      gi[(size_t)kk * G3H + row0 + r] = sel16(acc[r], kk);
  } else {
    const int u = (bx - 128) * 4 + wv;   // [0,768)
    gemv8<false>(h0, Whh0, nullptr, gh, G3H, u * 8, lane);
  }
}

// Layers 1/2: waves [0,768): gi = xprev @ Wih^T ; [768,1536): gh = h_l @ Whh^T.
__global__ __launch_bounds__(256, 2)
void gru_l12(const float* __restrict__ xprev, const float* __restrict__ hl,
             const float* __restrict__ Wih, const float* __restrict__ Whh,
             float* __restrict__ gi, float* __restrict__ gh)
{
  const int lane = threadIdx.x & 63;
  const int u = blockIdx.x * 4 + (threadIdx.x >> 6);
  if (u < 768) gemv8<false>(xprev, Wih, nullptr, gi, G3H, u * 8, lane);
  else         gemv8<false>(hl, Whh, nullptr, gh, G3H, (u - 768) * 8, lane);
}

// Gate math: h' = (1-z)*n + z*h. B*H threads.
__global__ __launch_bounds__(256)
void gru_epi(const float* __restrict__ gi, const float* __restrict__ gh,
             const float* __restrict__ bih, const float* __restrict__ bhh,
             const float* __restrict__ hprev, float* __restrict__ hout)
{
  const int idx = blockIdx.x * 256 + threadIdx.x;
  const int j = idx & (HH - 1);
  const size_t base = (size_t)(idx >> 11) * G3H;
  const float ir  = gi[base + j]          + bih[j];
  const float iz  = gi[base + HH + j]     + bih[HH + j];
  const float in_ = gi[base + 2 * HH + j] + bih[2 * HH + j];
  const float hr  = gh[base + j]          + bhh[j];
  const float hz  = gh[base + HH + j]     + bhh[HH + j];
  const float hn  = gh[base + 2 * HH + j] + bhh[2 * HH + j];
  const float r = 1.f / (1.f + expf(-(ir + hr)));
  const float z = 1.f / (1.f + expf(-(iz + hz)));
  const float n = tanhf(in_ + r * hn);
  hout[idx] = (1.f - z) * n + z * hprev[idx];
}

// Vocab projection: 4000 units x 8 rows. 1000 blocks.
__global__ __launch_bounds__(256, 2)
void out_kernel(const float* __restrict__ h2, const float* __restrict__ Wout,
                const float* __restrict__ bout, float* __restrict__ logits)
{
  const int lane = threadIdx.x & 63;
  const int u = blockIdx.x * 4 + (threadIdx.x >> 6);
  gemv8<true>(h2, Wout, bout, logits, VV, u * 8, lane);
}

// In-place log_softmax over each of the 16 rows (32000 wide).
__global__ __launch_bounds__(1024)
void lsm_kernel(float* __restrict__ logp)
{
  const int b   = blockIdx.x;
  const int tid = threadIdx.x;
  float* row = logp + (size_t)b * VV;
  const float4* r4 = (const float4*)row;
  __shared__ float red[16];
  const int wv = tid >> 6, ln = tid & 63;

  float m = -3.4e38f;
  for (int i = tid; i < VV / 4; i += 1024) {
    float4 v = r4[i];
    m = fmaxf(m, fmaxf(fmaxf(v.x, v.y), fmaxf(v.z, v.w)));
  }
  #pragma unroll
  for (int s = 1; s < 64; s <<= 1) m = fmaxf(m, __shfl_xor(m, s, 64));
  if (ln == 0) red[wv] = m;
  __syncthreads();
  if (tid == 0) {
    float mm = red[0];
    for (int w = 1; w < 16; ++w) mm = fmaxf(mm, red[w]);
    red[0] = mm;
  }
  __syncthreads();
  const float M = red[0];
  __syncthreads();

  float s = 0.f;
  for (int i = tid; i < VV / 4; i += 1024) {
    float4 v = r4[i];
    s += expf(v.x - M) + expf(v.y - M) + expf(v.z - M) + expf(v.w - M);
  }
  #pragma unroll
  for (int t = 1; t < 64; t <<= 1) s += __shfl_xor(s, t, 64);
  if (ln == 0) red[wv] = s;
  __syncthreads();
  if (tid == 0) {
    float ss = 0.f;
    for (int w = 0; w < 16; ++w) ss += red[w];
    red[0] = M + logf(ss);
  }
  __syncthreads();
  const float L = red[0];

  float4* w4 = (float4*)row;
  for (int i = tid; i < VV / 4; i += 1024) {
    float4 v = r4[i];
    v.x -= L; v.y -= L; v.z -= L; v.w -= L;
    w4[i] = v;
  }
}

extern "C" void kernel_launch(void* const* d_in, const int* in_sizes, int n_in,
                              void* d_out, int out_size, void* d_ws, size_t ws_size,
                              hipStream_t stream)
{
  const int*   tokens = (const int*)d_in[0];
  const float* hidden = (const float*)d_in[1]; // (3,B,H)
  const float* emb    = (const float*)d_in[2]; // (V,E)
  const float* Wih0 = (const float*)d_in[3];
  const float* Whh0 = (const float*)d_in[4];
  const float* bih0 = (const float*)d_in[5];
  const float* bhh0 = (const float*)d_in[6];
  const float* Wih1 = (const float*)d_in[7];
  const float* Whh1 = (const float*)d_in[8];
  const float* bih1 = (const float*)d_in[9];
  const float* bhh1 = (const float*)d_in[10];
  const float* Wih2 = (const float*)d_in[11];
  const float* Whh2 = (const float*)d_in[12];
  const float* bih2 = (const float*)d_in[13];
  const float* bhh2 = (const float*)d_in[14];
  const float* Wout = (const float*)d_in[15];
  const float* bout = (const float*)d_in[16];

  float* outp = (float*)d_out;
  float* logp = outp;                       // (B,V)
  float* hnew = outp + (size_t)BB * VV;     // (3,B,H)
  float* h0 = hnew;
  float* h1 = hnew + BB * HH;
  float* h2 = hnew + 2 * BB * HH;

  float* gi = (float*)d_ws;                 // (B,3H)
  float* gh = gi + (size_t)BB * G3H;        // (B,3H)

  gru_l0<<<320, 256, 0, stream>>>(emb, tokens, hidden, Wih0, Whh0, gi, gh);
  gru_epi<<<128, 256, 0, stream>>>(gi, gh, bih0, bhh0, hidden, h0);
  gru_l12<<<384, 256, 0, stream>>>(h0, hidden + BB * HH, Wih1, Whh1, gi, gh);
  gru_epi<<<128, 256, 0, stream>>>(gi, gh, bih1, bhh1, hidden + BB * HH, h1);
  gru_l12<<<384, 256, 0, stream>>>(h1, hidden + 2 * BB * HH, Wih2, Whh2, gi, gh);
  gru_epi<<<128, 256, 0, stream>>>(gi, gh, bih2, bhh2, hidden + 2 * BB * HH, h2);
  out_kernel<<<1000, 256, 0, stream>>>(h2, Wout, bout, logp);
  lsm_kernel<<<16, 1024, 0, stream>>>(logp);
}

// Round 6
// 346.089 us; speedup vs baseline: 1.0039x; 1.0039x over previous
//
#include <hip/hip_runtime.h>
#include <cmath>

// Decoder: 3-layer GRU (B=16, H=2048, E=128) + vocab projection (V=32000) + log_softmax.
// Memory-bound: 516 MB fp32 weights streamed once. Roofline ~78us @ ~6.8 TB/s.
//
// R5 post-mortem: acc[8][16] tile needed ~200 VGPRs, compiler allocated 124 ->
// spill/serialize (HBM 16-46%, VALU 14%, occ 18%). This version: 8 rows x 8
// batches per wave (acc 64 + xv 32 ~ 110 VGPR, fits 128 cap cleanly), sibling
// wave in the same block covers the other 8 batches so W rows are fetched once.
// All loads contiguous 1KB/wave-instr. 16 waves/CU for latency hiding.
// Reduction: fold-tree (63 folds), ends with exactly one output per lane.

#define BB 16
#define HH 2048
#define EE 128
#define VV 32000
#define G3H (3 * HH)

__device__ __forceinline__ void fma4(float& a, const float4 w, const float4 x) {
  a = fmaf(w.x, x.x, a); a = fmaf(w.y, x.y, a);
  a = fmaf(w.z, x.z, a); a = fmaf(w.w, x.w, a);
}

// fold two slot-values into one, halving slot count; lane bit m selects slot.
__device__ __forceinline__ float foldpair(float a, float b, int m, int lane) {
  float t = (lane & m) ? a : b;     // value we send
  t = __shfl_xor(t, m, 64);
  return ((lane & m) ? b : a) + t;  // value we keep + partner's
}

// static-index select (no runtime-indexed register arrays)
__device__ __forceinline__ float sel16(const float a[16], int i) {
  float s0 = (i & 1) ? a[1]  : a[0];
  float s1 = (i & 1) ? a[3]  : a[2];
  float s2 = (i & 1) ? a[5]  : a[4];
  float s3 = (i & 1) ? a[7]  : a[6];
  float s4 = (i & 1) ? a[9]  : a[8];
  float s5 = (i & 1) ? a[11] : a[10];
  float s6 = (i & 1) ? a[13] : a[12];
  float s7 = (i & 1) ? a[15] : a[14];
  float t0 = (i & 2) ? s1 : s0;
  float t1 = (i & 2) ? s3 : s2;
  float t2 = (i & 2) ? s5 : s4;
  float t3 = (i & 2) ? s7 : s6;
  float u0 = (i & 4) ? t1 : t0;
  float u1 = (i & 4) ? t3 : t2;
  return (i & 8) ? u1 : u0;
}

// 8 rows x 8 batches GEMV unit over DIM=2048. Lane L covers k = it*256 + L*4.
// half selects batches [half*8, half*8+8). All loads contiguous 1KB/instr.
template<bool BIAS>
__device__ __forceinline__
void gemv8x8(const float* __restrict__ x, const float* __restrict__ W,
             const float* __restrict__ bias, float* __restrict__ dst,
             int ldd, int row0, int half, int lane)
{
  float acc[64];
  #pragma unroll
  for (int i = 0; i < 64; ++i) acc[i] = 0.f;

  const int kb = lane * 4;
  const float* xb = x + (size_t)half * 8 * HH;

  #pragma unroll 1
  for (int it = 0; it < 8; ++it) {
    const int k = it * 256 + kb;
    float4 xv[8];
    #pragma unroll
    for (int b = 0; b < 8; ++b)
      xv[b] = *(const float4*)(xb + b * HH + k);
    #pragma unroll
    for (int r = 0; r < 8; ++r) {
      const float4 wv = *(const float4*)(W + (size_t)(row0 + r) * HH + k);
      #pragma unroll
      for (int b = 0; b < 8; ++b) fma4(acc[r * 8 + b], wv, xv[b]);
    }
  }

  // fold 64 slots -> 1 per lane (sum over all 64 lanes' k-partials)
  #pragma unroll
  for (int j = 0; j < 32; ++j) acc[j] = foldpair(acc[j], acc[j + 32], 1, lane);
  #pragma unroll
  for (int j = 0; j < 16; ++j) acc[j] = foldpair(acc[j], acc[j + 16], 2, lane);
  #pragma unroll
  for (int j = 0; j < 8; ++j)  acc[j] = foldpair(acc[j], acc[j + 8], 4, lane);
  #pragma unroll
  for (int j = 0; j < 4; ++j)  acc[j] = foldpair(acc[j], acc[j + 4], 8, lane);
  #pragma unroll
  for (int j = 0; j < 2; ++j)  acc[j] = foldpair(acc[j], acc[j + 2], 16, lane);
  acc[0] = foldpair(acc[0], acc[1], 32, lane);

  // lane L holds slot idx = 32*b0+16*b1+8*b2+4*b3+2*b4+1*b5 (bk = bit k of L)
  const int idx = ((lane & 1) << 5) | ((lane & 2) << 3) | ((lane & 4) << 1)
                | ((lane & 8) >> 1) | ((lane & 16) >> 3) | ((lane & 32) >> 5);
  const int r = idx >> 3;
  const int b = idx & 7;
  float o = acc[0];
  if (BIAS) o += bias[row0 + r];
  dst[(size_t)(half * 8 + b) * ldd + row0 + r] = o;
}

// Layer 0: blocks [0,128): gi = relu(emb[tok]) @ Wih0^T (3MB, DIM=128);
//          blocks [128,512): gh = hprev @ Whh0^T (50MB, gemv8x8).
__global__ __launch_bounds__(256, 4)
void gru_l0(const float* __restrict__ emb, const int* __restrict__ tokens,
            const float* __restrict__ hprev,
            const float* __restrict__ Wih0, const float* __restrict__ Whh0,
            float* __restrict__ gi, float* __restrict__ gh)
{
  const int tid  = threadIdx.x;
  const int lane = tid & 63;
  const int wv   = tid >> 6;
  const int bx   = blockIdx.x;

  if (bx < 128) {
    // 512 waves x 12 rows (rg owns 3), DIM=128; tiny (0.6% of traffic)
    const int kk = lane & 15;
    const int rg = lane >> 4;
    const int u  = bx * 4 + wv;
    const int row0 = u * 12 + rg * 3;
    float acc[3][16];
    #pragma unroll
    for (int r = 0; r < 3; ++r)
      #pragma unroll
      for (int b = 0; b < 16; ++b) acc[r][b] = 0.f;

    #pragma unroll
    for (int it = 0; it < 2; ++it) {
      const int k = it * 64 + kk * 4;
      const float4 w0 = *(const float4*)(Wih0 + (size_t)row0 * EE + k);
      const float4 w1 = *(const float4*)(Wih0 + (size_t)(row0 + 1) * EE + k);
      const float4 w2 = *(const float4*)(Wih0 + (size_t)(row0 + 2) * EE + k);
      #pragma unroll
      for (int b = 0; b < 16; ++b) {
        float4 xv = *(const float4*)(emb + (size_t)tokens[b] * EE + k);
        xv.x = fmaxf(xv.x, 0.f); xv.y = fmaxf(xv.y, 0.f);
        xv.z = fmaxf(xv.z, 0.f); xv.w = fmaxf(xv.w, 0.f);
        fma4(acc[0][b], w0, xv);
        fma4(acc[1][b], w1, xv);
        fma4(acc[2][b], w2, xv);
      }
    }
    #pragma unroll
    for (int r = 0; r < 3; ++r) {
      #pragma unroll
      for (int b = 0; b < 16; ++b) {
        float a = acc[r][b];
        a += __shfl_xor(a, 1, 64);
        a += __shfl_xor(a, 2, 64);
        a += __shfl_xor(a, 4, 64);
        a += __shfl_xor(a, 8, 64);
        acc[r][b] = a;
      }
    }
    #pragma unroll
    for (int r = 0; r < 3; ++r)
      gi[(size_t)kk * G3H + row0 + r] = sel16(acc[r], kk);
  } else {
    const int w = (bx - 128) * 4 + wv;   // [0,1536)
    gemv8x8<false>(hprev, Whh0, nullptr, gh, G3H, (w >> 1) * 8, w & 1, lane);
  }
}

// Layers 1/2: waves [0,1536): gi = xprev @ Wih^T; [1536,3072): gh = h_l @ Whh^T.
__global__ __launch_bounds__(256, 4)
void gru_l12(const float* __restrict__ xprev, const float* __restrict__ hl,
             const float* __restrict__ Wih, const float* __restrict__ Whh,
             float* __restrict__ gi, float* __restrict__ gh)
{
  const int lane = threadIdx.x & 63;
  const int w = blockIdx.x * 4 + (threadIdx.x >> 6);
  if (w < 1536) {
    gemv8x8<false>(xprev, Wih, nullptr, gi, G3H, (w >> 1) * 8, w & 1, lane);
  } else {
    const int u = w - 1536;
    gemv8x8<false>(hl, Whh, nullptr, gh, G3H, (u >> 1) * 8, u & 1, lane);
  }
}

// Gate math: h' = (1-z)*n + z*h. B*H threads.
__global__ __launch_bounds__(256)
void gru_epi(const float* __restrict__ gi, const float* __restrict__ gh,
             const float* __restrict__ bih, const float* __restrict__ bhh,
             const float* __restrict__ hprev, float* __restrict__ hout)
{
  const int idx = blockIdx.x * 256 + threadIdx.x;
  const int j = idx & (HH - 1);
  const size_t base = (size_t)(idx >> 11) * G3H;
  const float ir  = gi[base + j]          + bih[j];
  const float iz  = gi[base + HH + j]     + bih[HH + j];
  const float in_ = gi[base + 2 * HH + j] + bih[2 * HH + j];
  const float hr  = gh[base + j]          + bhh[j];
  const float hz  = gh[base + HH + j]     + bhh[HH + j];
  const float hn  = gh[base + 2 * HH + j] + bhh[2 * HH + j];
  const float r = 1.f / (1.f + expf(-(ir + hr)));
  const float z = 1.f / (1.f + expf(-(iz + hz)));
  const float n = tanhf(in_ + r * hn);
  hout[idx] = (1.f - z) * n + z * hprev[idx];
}

// Vocab projection: 4000 units x 2 halves = 8000 waves = 2000 blocks.
__global__ __launch_bounds__(256, 4)
void out_kernel(const float* __restrict__ h2, const float* __restrict__ Wout,
                const float* __restrict__ bout, float* __restrict__ logits)
{
  const int lane = threadIdx.x & 63;
  const int w = blockIdx.x * 4 + (threadIdx.x >> 6);
  gemv8x8<true>(h2, Wout, bout, logits, VV, (w >> 1) * 8, w & 1, lane);
}

// In-place log_softmax over each of the 16 rows (32000 wide).
__global__ __launch_bounds__(1024)
void lsm_kernel(float* __restrict__ logp)
{
  const int b   = blockIdx.x;
  const int tid = threadIdx.x;
  float* row = logp + (size_t)b * VV;
  const float4* r4 = (const float4*)row;
  __shared__ float red[16];
  const int wv = tid >> 6, ln = tid & 63;

  float m = -3.4e38f;
  for (int i = tid; i < VV / 4; i += 1024) {
    float4 v = r4[i];
    m = fmaxf(m, fmaxf(fmaxf(v.x, v.y), fmaxf(v.z, v.w)));
  }
  #pragma unroll
  for (int s = 1; s < 64; s <<= 1) m = fmaxf(m, __shfl_xor(m, s, 64));
  if (ln == 0) red[wv] = m;
  __syncthreads();
  if (tid == 0) {
    float mm = red[0];
    for (int w = 1; w < 16; ++w) mm = fmaxf(mm, red[w]);
    red[0] = mm;
  }
  __syncthreads();
  const float M = red[0];
  __syncthreads();

  float s = 0.f;
  for (int i = tid; i < VV / 4; i += 1024) {
    float4 v = r4[i];
    s += expf(v.x - M) + expf(v.y - M) + expf(v.z - M) + expf(v.w - M);
  }
  #pragma unroll
  for (int t = 1; t < 64; t <<= 1) s += __shfl_xor(s, t, 64);
  if (ln == 0) red[wv] = s;
  __syncthreads();
  if (tid == 0) {
    float ss = 0.f;
    for (int w = 0; w < 16; ++w) ss += red[w];
    red[0] = M + logf(ss);
  }
  __syncthreads();
  const float L = red[0];

  float4* w4 = (float4*)row;
  for (int i = tid; i < VV / 4; i += 1024) {
    float4 v = r4[i];
    v.x -= L; v.y -= L; v.z -= L; v.w -= L;
    w4[i] = v;
  }
}

extern "C" void kernel_launch(void* const* d_in, const int* in_sizes, int n_in,
                              void* d_out, int out_size, void* d_ws, size_t ws_size,
                              hipStream_t stream)
{
  const int*   tokens = (const int*)d_in[0];
  const float* hidden = (const float*)d_in[1]; // (3,B,H)
  const float* emb    = (const float*)d_in[2]; // (V,E)
  const float* Wih0 = (const float*)d_in[3];
  const float* Whh0 = (const float*)d_in[4];
  const float* bih0 = (const float*)d_in[5];
  const float* bhh0 = (const float*)d_in[6];
  const float* Wih1 = (const float*)d_in[7];
  const float* Whh1 = (const float*)d_in[8];
  const float* bih1 = (const float*)d_in[9];
  const float* bhh1 = (const float*)d_in[10];
  const float* Wih2 = (const float*)d_in[11];
  const float* Whh2 = (const float*)d_in[12];
  const float* bih2 = (const float*)d_in[13];
  const float* bhh2 = (const float*)d_in[14];
  const float* Wout = (const float*)d_in[15];
  const float* bout = (const float*)d_in[16];

  float* outp = (float*)d_out;
  float* logp = outp;                       // (B,V)
  float* hnew = outp + (size_t)BB * VV;     // (3,B,H)
  float* h0 = hnew;
  float* h1 = hnew + BB * HH;
  float* h2 = hnew + 2 * BB * HH;

  float* gi = (float*)d_ws;                 // (B,3H)
  float* gh = gi + (size_t)BB * G3H;        // (B,3H)

  gru_l0<<<512, 256, 0, stream>>>(emb, tokens, hidden, Wih0, Whh0, gi, gh);
  gru_epi<<<128, 256, 0, stream>>>(gi, gh, bih0, bhh0, hidden, h0);
  gru_l12<<<768, 256, 0, stream>>>(h0, hidden + BB * HH, Wih1, Whh1, gi, gh);
  gru_epi<<<128, 256, 0, stream>>>(gi, gh, bih1, bhh1, hidden + BB * HH, h1);
  gru_l12<<<768, 256, 0, stream>>>(h1, hidden + 2 * BB * HH, Wih2, Whh2, gi, gh);
  gru_epi<<<128, 256, 0, stream>>>(gi, gh, bih2, bhh2, hidden + 2 * BB * HH, h2);
  out_kernel<<<2000, 256, 0, stream>>>(h2, Wout, bout, logp);
  lsm_kernel<<<16, 1024, 0, stream>>>(logp);
}

// Round 7
// 197.643 us; speedup vs baseline: 1.7578x; 1.7511x over previous
//
#include <hip/hip_runtime.h>
#include <cmath>

// Decoder: 3-layer GRU (B=16, H=2048, E=128) + vocab projection (V=32000) + log_softmax.
// Memory-bound: 516 MB fp32 weights streamed once. Roofline ~78us @ ~6.8 TB/s.
//
// R5/R6 post-mortem: BOTH rounds spilled. R5: WRITE_SIZE=359MB of scratch on a
// 2MB-output kernel (acc[128] tile vs 124 VGPRs). R6: smaller tile (acc[64],
// live ~135-150 incl. hoisted address pairs) but __launch_bounds__(256,4)
// capped VGPRs at 128 -> still spilled. Fix: launch_bounds(256,2) (cap 256).
// Need ~135 -> no spill, ~3 waves/SIMD, 16KB contiguous loads in flight/wave.

#define BB 16
#define HH 2048
#define EE 128
#define VV 32000
#define G3H (3 * HH)

__device__ __forceinline__ void fma4(float& a, const float4 w, const float4 x) {
  a = fmaf(w.x, x.x, a); a = fmaf(w.y, x.y, a);
  a = fmaf(w.z, x.z, a); a = fmaf(w.w, x.w, a);
}

// fold two slot-values into one, halving slot count; lane bit m selects slot.
__device__ __forceinline__ float foldpair(float a, float b, int m, int lane) {
  float t = (lane & m) ? a : b;     // value we send
  t = __shfl_xor(t, m, 64);
  return ((lane & m) ? b : a) + t;  // value we keep + partner's
}

// static-index select (no runtime-indexed register arrays)
__device__ __forceinline__ float sel16(const float a[16], int i) {
  float s0 = (i & 1) ? a[1]  : a[0];
  float s1 = (i & 1) ? a[3]  : a[2];
  float s2 = (i & 1) ? a[5]  : a[4];
  float s3 = (i & 1) ? a[7]  : a[6];
  float s4 = (i & 1) ? a[9]  : a[8];
  float s5 = (i & 1) ? a[11] : a[10];
  float s6 = (i & 1) ? a[13] : a[12];
  float s7 = (i & 1) ? a[15] : a[14];
  float t0 = (i & 2) ? s1 : s0;
  float t1 = (i & 2) ? s3 : s2;
  float t2 = (i & 2) ? s5 : s4;
  float t3 = (i & 2) ? s7 : s6;
  float u0 = (i & 4) ? t1 : t0;
  float u1 = (i & 4) ? t3 : t2;
  return (i & 8) ? u1 : u0;
}

// 8 rows x 8 batches GEMV unit over DIM=2048. Lane L covers k = it*256 + L*4.
// half selects batches [half*8, half*8+8). All loads contiguous 1KB/instr.
template<bool BIAS>
__device__ __forceinline__
void gemv8x8(const float* __restrict__ x, const float* __restrict__ W,
             const float* __restrict__ bias, float* __restrict__ dst,
             int ldd, int row0, int half, int lane)
{
  float acc[64];
  #pragma unroll
  for (int i = 0; i < 64; ++i) acc[i] = 0.f;

  const int kb = lane * 4;
  const float* xb = x + (size_t)half * 8 * HH;

  #pragma unroll 1
  for (int it = 0; it < 8; ++it) {
    const int k = it * 256 + kb;
    float4 xv[8];
    #pragma unroll
    for (int b = 0; b < 8; ++b)
      xv[b] = *(const float4*)(xb + b * HH + k);
    #pragma unroll
    for (int r = 0; r < 8; ++r) {
      const float4 wv = *(const float4*)(W + (size_t)(row0 + r) * HH + k);
      #pragma unroll
      for (int b = 0; b < 8; ++b) fma4(acc[r * 8 + b], wv, xv[b]);
    }
  }

  // fold 64 slots -> 1 per lane (sum over all 64 lanes' k-partials)
  #pragma unroll
  for (int j = 0; j < 32; ++j) acc[j] = foldpair(acc[j], acc[j + 32], 1, lane);
  #pragma unroll
  for (int j = 0; j < 16; ++j) acc[j] = foldpair(acc[j], acc[j + 16], 2, lane);
  #pragma unroll
  for (int j = 0; j < 8; ++j)  acc[j] = foldpair(acc[j], acc[j + 8], 4, lane);
  #pragma unroll
  for (int j = 0; j < 4; ++j)  acc[j] = foldpair(acc[j], acc[j + 4], 8, lane);
  #pragma unroll
  for (int j = 0; j < 2; ++j)  acc[j] = foldpair(acc[j], acc[j + 2], 16, lane);
  acc[0] = foldpair(acc[0], acc[1], 32, lane);

  // lane L holds slot idx = 32*b0+16*b1+8*b2+4*b3+2*b4+1*b5 (bk = bit k of L)
  const int idx = ((lane & 1) << 5) | ((lane & 2) << 3) | ((lane & 4) << 1)
                | ((lane & 8) >> 1) | ((lane & 16) >> 3) | ((lane & 32) >> 5);
  const int r = idx >> 3;
  const int b = idx & 7;
  float o = acc[0];
  if (BIAS) o += bias[row0 + r];
  dst[(size_t)(half * 8 + b) * ldd + row0 + r] = o;
}

// Layer 0: blocks [0,128): gi = relu(emb[tok]) @ Wih0^T (3MB, DIM=128);
//          blocks [128,512): gh = hprev @ Whh0^T (50MB, gemv8x8).
__global__ __launch_bounds__(256, 2)
void gru_l0(const float* __restrict__ emb, const int* __restrict__ tokens,
            const float* __restrict__ hprev,
            const float* __restrict__ Wih0, const float* __restrict__ Whh0,
            float* __restrict__ gi, float* __restrict__ gh)
{
  const int tid  = threadIdx.x;
  const int lane = tid & 63;
  const int wv   = tid >> 6;
  const int bx   = blockIdx.x;

  if (bx < 128) {
    // 512 waves x 12 rows (rg owns 3), DIM=128; tiny (0.6% of traffic)
    const int kk = lane & 15;
    const int rg = lane >> 4;
    const int u  = bx * 4 + wv;
    const int row0 = u * 12 + rg * 3;
    float acc[3][16];
    #pragma unroll
    for (int r = 0; r < 3; ++r)
      #pragma unroll
      for (int b = 0; b < 16; ++b) acc[r][b] = 0.f;

    #pragma unroll
    for (int it = 0; it < 2; ++it) {
      const int k = it * 64 + kk * 4;
      const float4 w0 = *(const float4*)(Wih0 + (size_t)row0 * EE + k);
      const float4 w1 = *(const float4*)(Wih0 + (size_t)(row0 + 1) * EE + k);
      const float4 w2 = *(const float4*)(Wih0 + (size_t)(row0 + 2) * EE + k);
      #pragma unroll
      for (int b = 0; b < 16; ++b) {
        float4 xv = *(const float4*)(emb + (size_t)tokens[b] * EE + k);
        xv.x = fmaxf(xv.x, 0.f); xv.y = fmaxf(xv.y, 0.f);
        xv.z = fmaxf(xv.z, 0.f); xv.w = fmaxf(xv.w, 0.f);
        fma4(acc[0][b], w0, xv);
        fma4(acc[1][b], w1, xv);
        fma4(acc[2][b], w2, xv);
      }
    }
    #pragma unroll
    for (int r = 0; r < 3; ++r) {
      #pragma unroll
      for (int b = 0; b < 16; ++b) {
        float a = acc[r][b];
        a += __shfl_xor(a, 1, 64);
        a += __shfl_xor(a, 2, 64);
        a += __shfl_xor(a, 4, 64);
        a += __shfl_xor(a, 8, 64);
        acc[r][b] = a;
      }
    }
    #pragma unroll
    for (int r = 0; r < 3; ++r)
      gi[(size_t)kk * G3H + row0 + r] = sel16(acc[r], kk);
  } else {
    const int w = (bx - 128) * 4 + wv;   // [0,1536)
    gemv8x8<false>(hprev, Whh0, nullptr, gh, G3H, (w >> 1) * 8, w & 1, lane);
  }
}

// Layers 1/2: waves [0,1536): gi = xprev @ Wih^T; [1536,3072): gh = h_l @ Whh^T.
__global__ __launch_bounds__(256, 2)
void gru_l12(const float* __restrict__ xprev, const float* __restrict__ hl,
             const float* __restrict__ Wih, const float* __restrict__ Whh,
             float* __restrict__ gi, float* __restrict__ gh)
{
  const int lane = threadIdx.x & 63;
  const int w = blockIdx.x * 4 + (threadIdx.x >> 6);
  if (w < 1536) {
    gemv8x8<false>(xprev, Wih, nullptr, gi, G3H, (w >> 1) * 8, w & 1, lane);
  } else {
    const int u = w - 1536;
    gemv8x8<false>(hl, Whh, nullptr, gh, G3H, (u >> 1) * 8, u & 1, lane);
  }
}

// Gate math: h' = (1-z)*n + z*h. B*H threads.
__global__ __launch_bounds__(256)
void gru_epi(const float* __restrict__ gi, const float* __restrict__ gh,
             const float* __restrict__ bih, const float* __restrict__ bhh,
             const float* __restrict__ hprev, float* __restrict__ hout)
{
  const int idx = blockIdx.x * 256 + threadIdx.x;
  const int j = idx & (HH - 1);
  const size_t base = (size_t)(idx >> 11) * G3H;
  const float ir  = gi[base + j]          + bih[j];
  const float iz  = gi[base + HH + j]     + bih[HH + j];
  const float in_ = gi[base + 2 * HH + j] + bih[2 * HH + j];
  const float hr  = gh[base + j]          + bhh[j];
  const float hz  = gh[base + HH + j]     + bhh[HH + j];
  const float hn  = gh[base + 2 * HH + j] + bhh[2 * HH + j];
  const float r = 1.f / (1.f + expf(-(ir + hr)));
  const float z = 1.f / (1.f + expf(-(iz + hz)));
  const float n = tanhf(in_ + r * hn);
  hout[idx] = (1.f - z) * n + z * hprev[idx];
}

// Vocab projection: 4000 units x 2 halves = 8000 waves = 2000 blocks.
__global__ __launch_bounds__(256, 2)
void out_kernel(const float* __restrict__ h2, const float* __restrict__ Wout,
                const float* __restrict__ bout, float* __restrict__ logits)
{
  const int lane = threadIdx.x & 63;
  const int w = blockIdx.x * 4 + (threadIdx.x >> 6);
  gemv8x8<true>(h2, Wout, bout, logits, VV, (w >> 1) * 8, w & 1, lane);
}

// In-place log_softmax over each of the 16 rows (32000 wide).
__global__ __launch_bounds__(1024)
void lsm_kernel(float* __restrict__ logp)
{
  const int b   = blockIdx.x;
  const int tid = threadIdx.x;
  float* row = logp + (size_t)b * VV;
  const float4* r4 = (const float4*)row;
  __shared__ float red[16];
  const int wv = tid >> 6, ln = tid & 63;

  float m = -3.4e38f;
  for (int i = tid; i < VV / 4; i += 1024) {
    float4 v = r4[i];
    m = fmaxf(m, fmaxf(fmaxf(v.x, v.y), fmaxf(v.z, v.w)));
  }
  #pragma unroll
  for (int s = 1; s < 64; s <<= 1) m = fmaxf(m, __shfl_xor(m, s, 64));
  if (ln == 0) red[wv] = m;
  __syncthreads();
  if (tid == 0) {
    float mm = red[0];
    for (int w = 1; w < 16; ++w) mm = fmaxf(mm, red[w]);
    red[0] = mm;
  }
  __syncthreads();
  const float M = red[0];
  __syncthreads();

  float s = 0.f;
  for (int i = tid; i < VV / 4; i += 1024) {
    float4 v = r4[i];
    s += expf(v.x - M) + expf(v.y - M) + expf(v.z - M) + expf(v.w - M);
  }
  #pragma unroll
  for (int t = 1; t < 64; t <<= 1) s += __shfl_xor(s, t, 64);
  if (ln == 0) red[wv] = s;
  __syncthreads();
  if (tid == 0) {
    float ss = 0.f;
    for (int w = 0; w < 16; ++w) ss += red[w];
    red[0] = M + logf(ss);
  }
  __syncthreads();
  const float L = red[0];

  float4* w4 = (float4*)row;
  for (int i = tid; i < VV / 4; i += 1024) {
    float4 v = r4[i];
    v.x -= L; v.y -= L; v.z -= L; v.w -= L;
    w4[i] = v;
  }
}

extern "C" void kernel_launch(void* const* d_in, const int* in_sizes, int n_in,
                              void* d_out, int out_size, void* d_ws, size_t ws_size,
                              hipStream_t stream)
{
  const int*   tokens = (const int*)d_in[0];
  const float* hidden = (const float*)d_in[1]; // (3,B,H)
  const float* emb    = (const float*)d_in[2]; // (V,E)
  const float* Wih0 = (const float*)d_in[3];
  const float* Whh0 = (const float*)d_in[4];
  const float* bih0 = (const float*)d_in[5];
  const float* bhh0 = (const float*)d_in[6];
  const float* Wih1 = (const float*)d_in[7];
  const float* Whh1 = (const float*)d_in[8];
  const float* bih1 = (const float*)d_in[9];
  const float* bhh1 = (const float*)d_in[10];
  const float* Wih2 = (const float*)d_in[11];
  const float* Whh2 = (const float*)d_in[12];
  const float* bih2 = (const float*)d_in[13];
  const float* bhh2 = (const float*)d_in[14];
  const float* Wout = (const float*)d_in[15];
  const float* bout = (const float*)d_in[16];

  float* outp = (float*)d_out;
  float* logp = outp;                       // (B,V)
  float* hnew = outp + (size_t)BB * VV;     // (3,B,H)
  float* h0 = hnew;
  float* h1 = hnew + BB * HH;
  float* h2 = hnew + 2 * BB * HH;

  float* gi = (float*)d_ws;                 // (B,3H)
  float* gh = gi + (size_t)BB * G3H;        // (B,3H)

  gru_l0<<<512, 256, 0, stream>>>(emb, tokens, hidden, Wih0, Whh0, gi, gh);
  gru_epi<<<128, 256, 0, stream>>>(gi, gh, bih0, bhh0, hidden, h0);
  gru_l12<<<768, 256, 0, stream>>>(h0, hidden + BB * HH, Wih1, Whh1, gi, gh);
  gru_epi<<<128, 256, 0, stream>>>(gi, gh, bih1, bhh1, hidden + BB * HH, h1);
  gru_l12<<<768, 256, 0, stream>>>(h1, hidden + 2 * BB * HH, Wih2, Whh2, gi, gh);
  gru_epi<<<128, 256, 0, stream>>>(gi, gh, bih2, bhh2, hidden + 2 * BB * HH, h2);
  out_kernel<<<2000, 256, 0, stream>>>(h2, Wout, bout, logp);
  lsm_kernel<<<16, 1024, 0, stream>>>(logp);
}